// Round 18
// baseline (148.105 us; speedup 1.0000x reference)
//
#include <hip/hip_runtime.h>
#include <hip/hip_bf16.h>

typedef __bf16 bf16x8 __attribute__((ext_vector_type(8)));
typedef float  f32x4  __attribute__((ext_vector_type(4)));
typedef unsigned short ushort_t;

#define NN 468

// wext element offsets (ushort), fragment-major planes (NOT swizzled)
#define W1H 0
#define W1L 8192
#define W2H 16384
#define W2L 49152
#define W3H 81920
#define W3L 114688

// ---- per-unit LDS offsets (relative to unit base); unit span 77,768 B ----
// X @0 (max X2 43296) | Y1 @32096 (2x14336) | Y2 @27200 (2x24576, full K)
// Y3 @43296 (2x16384) | lmst @76352 (1416)
// Overlays are time-safe: Y1 dead before X1 grows past 27200? X1=[100][68]
// ends 27200 (< Y1 @32096) ✓; Y2 dead (GEMM2) before X2 [0,43296) written ✓;
// Y3 written after X2 (disjoint) ✓.
#define UO_Y1 32096
#define UO_Y2 27200
#define UO_Y3 43296
#define UO_LM 76352
#define U_STRIDE 77768
#define L_DTAB  (2*U_STRIDE)        // 155536, 472 B
#define L_POOLA (L_DTAB + 472)      // 156008, 512 B
#define L_POOLB (L_POOLA + 512)     // 156520, 512 B -> total 157032

#define MFMA3(d, ah, al, wh, wl)                                        \
    d = __builtin_amdgcn_mfma_f32_16x16x32_bf16(ah, wh, d, 0, 0, 0);    \
    d = __builtin_amdgcn_mfma_f32_16x16x32_bf16(ah, wl, d, 0, 0, 0);    \
    d = __builtin_amdgcn_mfma_f32_16x16x32_bf16(al, wh, d, 0, 0, 0);

// ---------------------------------------------------------------------------
__device__ __forceinline__ void pack_split4(const float* y,
                                            ushort_t* hdst, ushort_t* ldst) {
    ushort_t h[4], l[4];
    #pragma unroll
    for (int j = 0; j < 4; ++j) {
        __hip_bfloat16 hb = __float2bfloat16(y[j]);
        float hf = __bfloat162float(hb);
        __hip_bfloat16 lb = __float2bfloat16(y[j] - hf);
        h[j] = *(ushort_t*)&hb; l[j] = *(ushort_t*)&lb;
    }
    uint2 hv = make_uint2((unsigned)h[0] | ((unsigned)h[1] << 16),
                          (unsigned)h[2] | ((unsigned)h[3] << 16));
    uint2 lv = make_uint2((unsigned)l[0] | ((unsigned)l[1] << 16),
                          (unsigned)l[2] | ((unsigned)l[3] << 16));
    *(uint2*)hdst = hv;
    *(uint2*)ldst = lv;
}

__device__ __forceinline__ int frag_off(int r, int k, int K16) {
    return (r >> 4) * K16 + (k >> 5) * 512 + ((k >> 3) & 3) * 128
         + (r & 15) * 8 + (k & 7);
}

// swizzled Y-plane offset (LDS): unit' = q*16 + ((r ^ 2q) & 15)
__device__ __forceinline__ int ywoff(int r, int k4, int K16) {
    int q = (k4 >> 3) & 3;
    int u = q * 16 + (((r & 15) ^ (q << 1)) & 15);
    return (r >> 4) * K16 + (k4 >> 5) * 512 + u * 8 + (k4 & 7);
}

// ---------------------------------------------------------------------------
// Phase functions — bodies identical to R16 (verified), parameterized by unit.
// Frames: X0 l0: gr=r0-27+l0 (0..117) | Y1/X1 lr1: gr=r0-18+lr1 (0..99/112)
//         Y2/X2 lr2: gr=r0-9+lr2 (0..81/96) | Y3 lr3: gr=r0+lr3 (0..63)
// ---------------------------------------------------------------------------
__device__ __forceinline__ void ph_stage(const float* Lm, float* lmst,
                                         float* pool, float* dtab, bool do_dtab,
                                         int b, int r0) {
    int tid = threadIdx.x;
    if (do_dtab && tid < 118) {
        int ri = r0 - 27 + tid;
        float dv = 0.f;
        if (ri >= 0 && ri < NN) {
            int lo = ri - 9; if (lo < 0) lo = 0;
            int hi = ri + 9; if (hi > NN - 1) hi = NN - 1;
            dv = 1.0f / sqrtf((float)(hi - lo + 1));
        }
        dtab[tid] = dv;
    }
    if (tid < 354) {
        int g = (r0 - 27) * 3 + tid;
        lmst[tid] = (g >= 0 && g < NN * 3) ? Lm[(size_t)b * (NN * 3) + g] : 0.f;
    }
    if (tid < 128) pool[tid] = 0.f;
}

__device__ __forceinline__ void ph_enc(float* X, const float* lmst,
                                       const float* dtab, const float* We,
                                       const float* be) {
    int tid = threadIdx.x;
    const int c = tid & 63;
    const float w0 = We[c], w1 = We[64 + c], w2 = We[128 + c], bk = be[c];
    for (int l0 = tid >> 6; l0 < 118; l0 += 8) {
        float x = bk + lmst[l0*3]*w0 + lmst[l0*3+1]*w1 + lmst[l0*3+2]*w2;
        X[l0 * 68 + c] = x * dtab[l0];
    }
}

__device__ __forceinline__ void ph_band1(const float* X, ushort_t* Y1h,
                                         ushort_t* Y1l, const float* dtab) {
    int tid = threadIdx.x;
    const int c4 = (tid & 15) << 2;
    const int base = (tid >> 4) * 4;
    if (base < 100) {
        f32x4 ws = {};
        #pragma unroll
        for (int d = 0; d < 19; ++d)
            ws += *(const f32x4*)(X + (base + d) * 68 + c4);
        #pragma unroll
        for (int rr = 0; rr < 4; ++rr) {
            int row = base + rr;
            if (rr) ws += *(const f32x4*)(X + (row + 18) * 68 + c4)
                        - *(const f32x4*)(X + (row - 1)  * 68 + c4);
            float dv = dtab[row + 9];
            float y4[4] = {ws[0]*dv, ws[1]*dv, ws[2]*dv, ws[3]*dv};
            int off = ywoff(row, c4, 1024);
            pack_split4(y4, Y1h + off, Y1l + off);
        }
    } else if (base < 112) {
        float z4[4] = {0.f, 0.f, 0.f, 0.f};
        #pragma unroll
        for (int rr = 0; rr < 4; ++rr) {
            int row = base + rr;
            if (row < 112) {
                int off = ywoff(row, c4, 1024);
                pack_split4(z4, Y1h + off, Y1l + off);
            }
        }
    }
}

__device__ __forceinline__ void ph_gemm1(const ushort_t* Y1h, const ushort_t* Y1l,
                                         const ushort_t* wext, f32x4 (&acc1)[4][2]) {
    int tid = threadIdx.x;
    const int lane = tid & 63, wave = tid >> 6;
    const int wm = wave & 1, wn = wave >> 1;
    const int lswz = (lane & 48) + (((lane & 15) ^ ((lane >> 4) << 1)) & 15);
    __builtin_amdgcn_s_setprio(1);
    #pragma unroll
    for (int kt = 0; kt < 2; ++kt) {
        bf16x8 a[4][2];
        #pragma unroll
        for (int mt = 0; mt < 4; ++mt) {
            int t = wm*4 + mt; if (t > 6) t = 6;
            int off = t * 1024 + kt * 512 + lswz * 8;
            a[mt][0] = *(const bf16x8*)(Y1h + off);
            a[mt][1] = *(const bf16x8*)(Y1l + off);
        }
        #pragma unroll
        for (int nt = 0; nt < 2; ++nt) {
            int woff = (nt*4 + wn) * 1024 + kt * 512 + lane * 8;
            bf16x8 wh = *(const bf16x8*)(wext + W1H + woff);
            bf16x8 wl = *(const bf16x8*)(wext + W1L + woff);
            #pragma unroll
            for (int mt = 0; mt < 4; ++mt) {
                MFMA3(acc1[mt][nt], a[mt][0], a[mt][1], wh, wl);
            }
        }
    }
    __builtin_amdgcn_s_setprio(0);
}

__device__ __forceinline__ void ph_epi1(float* X, const f32x4 (&acc1)[4][2],
                                        const float* dtab, const float* b1, int kc) {
    int tid = threadIdx.x;
    const int lane = tid & 63, wave = tid >> 6;
    const int wm = wave & 1, wn = wave >> 1;
    const int l15 = lane & 15, lg = lane >> 4;
    #pragma unroll
    for (int mt = 0; mt < 4; ++mt) {
        int t = wm*4 + mt; if (t > 6) t = 6;
        int gcol = (kc*4 + wn)*16 + l15;
        int cl   = wn*16 + l15;
        float bv = b1[gcol];
        #pragma unroll
        for (int r = 0; r < 4; ++r) {
            int lr1 = t*16 + lg*4 + r;
            if (lr1 < 100)
                X[lr1*68 + cl] = dtab[lr1 + 9] * fmaxf(acc1[mt][kc][r] + bv, 0.f);
        }
    }
}

__device__ __forceinline__ void ph_band2(const float* X, ushort_t* Y2h,
                                         ushort_t* Y2l, const float* dtab, int kc) {
    int tid = threadIdx.x;
    const int c4   = (tid & 15) << 2;
    const int base = (tid >> 4) * 3;
    f32x4 ws = {};
    if (base < 82) {
        #pragma unroll
        for (int d = 0; d < 19; ++d)
            ws += *(const f32x4*)(X + (base + d) * 68 + c4);
    }
    #pragma unroll
    for (int rr = 0; rr < 3; ++rr) {
        int row = base + rr;
        if (row < 96) {
            float y4[4] = {0.f, 0.f, 0.f, 0.f};
            if (row < 82) {
                if (rr) ws += *(const f32x4*)(X + (row + 18) * 68 + c4)
                            - *(const f32x4*)(X + (row - 1)  * 68 + c4);
                float dv = dtab[row + 18];
                y4[0] = ws[0]*dv; y4[1] = ws[1]*dv;
                y4[2] = ws[2]*dv; y4[3] = ws[3]*dv;
            }
            int off = ywoff(row, kc*64 + c4, 2048);
            pack_split4(y4, Y2h + off, Y2l + off);
        }
    }
}

__device__ __forceinline__ void ph_gemm2(const ushort_t* Y2h, const ushort_t* Y2l,
                                         const ushort_t* wext, f32x4 (&acc2)[3][4]) {
    int tid = threadIdx.x;
    const int lane = tid & 63, wave = tid >> 6;
    const int wm = wave & 1, wn = wave >> 1;
    const int lswz = (lane & 48) + (((lane & 15) ^ ((lane >> 4) << 1)) & 15);
    __builtin_amdgcn_s_setprio(1);
    #pragma unroll
    for (int kt = 0; kt < 4; ++kt) {
        bf16x8 a[3][2];
        #pragma unroll
        for (int mt = 0; mt < 3; ++mt) {
            int off = (wm*3 + mt) * 2048 + kt * 512 + lswz * 8;
            a[mt][0] = *(const bf16x8*)(Y2h + off);
            a[mt][1] = *(const bf16x8*)(Y2l + off);
        }
        #pragma unroll
        for (int nt = 0; nt < 4; ++nt) {
            int woff = (nt*4 + wn) * 2048 + kt * 512 + lane * 8;
            bf16x8 wh = *(const bf16x8*)(wext + W2H + woff);
            bf16x8 wl = *(const bf16x8*)(wext + W2L + woff);
            #pragma unroll
            for (int mt = 0; mt < 3; ++mt) {
                MFMA3(acc2[mt][nt], a[mt][0], a[mt][1], wh, wl);
            }
        }
    }
    __builtin_amdgcn_s_setprio(0);
}

__device__ __forceinline__ void ph_epi2(float* X, const f32x4 (&acc2)[3][4],
                                        const float* dtab, const float* b2, int nc) {
    int tid = threadIdx.x;
    const int lane = tid & 63, wave = tid >> 6;
    const int wm = wave & 1, wn = wave >> 1;
    const int l15 = lane & 15, lg = lane >> 4;
    #pragma unroll
    for (int mt = 0; mt < 3; ++mt)
    #pragma unroll
    for (int q = 0; q < 2; ++q) {
        int gcol = ((nc*2 + q)*4 + wn)*16 + l15;
        int cl   = (q*4 + wn)*16 + l15;
        float bv = b2[gcol];
        #pragma unroll
        for (int r = 0; r < 4; ++r) {
            int lr2 = (wm*3 + mt)*16 + lg*4 + r;
            if (lr2 < 82)
                X[lr2*132 + cl] = dtab[lr2 + 18] * fmaxf(acc2[mt][nc*2 + q][r] + bv, 0.f);
        }
    }
}

__device__ __forceinline__ void ph_band3(const float* X, ushort_t* Y3h,
                                         ushort_t* Y3l, const float* dtab) {
    int tid = threadIdx.x;
    const int c4   = (tid & 31) << 2;
    const int base = (tid >> 5) * 4;
    f32x4 ws = {};
    #pragma unroll
    for (int d = 0; d < 19; ++d)
        ws += *(const f32x4*)(X + (base + d) * 132 + c4);
    #pragma unroll
    for (int rr = 0; rr < 4; ++rr) {
        int row = base + rr;
        if (rr) ws += *(const f32x4*)(X + (row + 18) * 132 + c4)
                    - *(const f32x4*)(X + (row - 1)  * 132 + c4);
        float dv = dtab[row + 27];
        float y4[4] = {ws[0]*dv, ws[1]*dv, ws[2]*dv, ws[3]*dv};
        int off = ywoff(row, c4, 2048);
        pack_split4(y4, Y3h + off, Y3l + off);
    }
}

__device__ __forceinline__ void ph_gemm3(const ushort_t* Y3h, const ushort_t* Y3l,
                                         const ushort_t* wext, f32x4 (&acc3)[2][2],
                                         int nc) {
    int tid = threadIdx.x;
    const int lane = tid & 63, wave = tid >> 6;
    const int wm = wave & 1, wn = wave >> 1;
    const int lswz = (lane & 48) + (((lane & 15) ^ ((lane >> 4) << 1)) & 15);
    __builtin_amdgcn_s_setprio(1);
    #pragma unroll
    for (int kt = 0; kt < 4; ++kt) {
        bf16x8 a0[2], a1[2];
        #pragma unroll
        for (int mt = 0; mt < 2; ++mt) {
            int aoff = (wm*2 + mt) * 2048 + kt * 512 + lswz * 8;
            a0[mt] = *(const bf16x8*)(Y3h + aoff);
            a1[mt] = *(const bf16x8*)(Y3l + aoff);
        }
        #pragma unroll
        for (int nt = 0; nt < 2; ++nt) {
            int woff = (nt*4 + wn) * 4096 + (nc*4 + kt) * 512 + lane * 8;
            bf16x8 wh = *(const bf16x8*)(wext + W3H + woff);
            bf16x8 wl = *(const bf16x8*)(wext + W3L + woff);
            #pragma unroll
            for (int mt = 0; mt < 2; ++mt) {
                MFMA3(acc3[mt][nt], a0[mt], a1[mt], wh, wl);
            }
        }
    }
    __builtin_amdgcn_s_setprio(0);
}

__device__ __forceinline__ void ph_pool(const f32x4 (&acc3)[2][2], float* pool,
                                        const float* b3, float* partial,
                                        int b, int rt, int r0) {
    int tid = threadIdx.x;
    const int lane = tid & 63, wave = tid >> 6;
    const int wm = wave & 1, wn = wave >> 1;
    const int l15 = lane & 15, lg = lane >> 4;
    #pragma unroll
    for (int nt = 0; nt < 2; ++nt) {
        int g_t = nt*4 + wn;
        float bv = b3[g_t*16 + l15];
        float cs = 0.f;
        #pragma unroll
        for (int mt = 0; mt < 2; ++mt)
        #pragma unroll
        for (int r = 0; r < 4; ++r) {
            int gr = r0 + (wm*2 + mt)*16 + lg*4 + r;
            if (gr < NN) cs += fmaxf(acc3[mt][nt][r] + bv, 0.f);
        }
        cs += __shfl_xor(cs, 16);
        cs += __shfl_xor(cs, 32);
        if (lane < 16) atomicAdd(&pool[g_t*16 + lane], cs);
    }
    __syncthreads();
    if (tid < 128) partial[((size_t)b * 8 + rt) * 128 + tid] = pool[tid];
}

// ---------------------------------------------------------------------------
// fused2: TWO (tile, batch) units per block, unit B shifted 5 slots behind A.
// Forces MFMA∥VALU antiphase that 2 lockstep blocks never achieved (R16 PM).
// LDS 157,032 B -> 1 block/CU. launch_bounds(512,2): 256-reg cap, no spill.
// ---------------------------------------------------------------------------
__global__ __launch_bounds__(512, 2) void fused2(
    const float* __restrict__ Lm, const ushort_t* __restrict__ wext,
    const float* __restrict__ We, const float* __restrict__ be,
    const float* __restrict__ b1, const float* __restrict__ b2,
    const float* __restrict__ b3, float* __restrict__ partial)
{
    __shared__ __align__(16) char lds[157056];
    char* uA = lds;
    char* uB = lds + U_STRIDE;
    float*    XA   = (float*)(uA);
    ushort_t* Y1hA = (ushort_t*)(uA + UO_Y1);  ushort_t* Y1lA = Y1hA + 7168;
    ushort_t* Y2hA = (ushort_t*)(uA + UO_Y2);  ushort_t* Y2lA = Y2hA + 12288;
    ushort_t* Y3hA = (ushort_t*)(uA + UO_Y3);  ushort_t* Y3lA = Y3hA + 8192;
    float*    lmA  = (float*)(uA + UO_LM);
    float*    XB   = (float*)(uB);
    ushort_t* Y1hB = (ushort_t*)(uB + UO_Y1);  ushort_t* Y1lB = Y1hB + 7168;
    ushort_t* Y2hB = (ushort_t*)(uB + UO_Y2);  ushort_t* Y2lB = Y2hB + 12288;
    ushort_t* Y3hB = (ushort_t*)(uB + UO_Y3);  ushort_t* Y3lB = Y3hB + 8192;
    float*    lmB  = (float*)(uB + UO_LM);
    float*    dtab = (float*)(lds + L_DTAB);
    float*    poolA = (float*)(lds + L_POOLA);
    float*    poolB = (float*)(lds + L_POOLB);

    const int rt = blockIdx.x;
    const int bA = blockIdx.y * 2, bB = bA + 1;
    const int r0 = rt * 64;

    f32x4 acc1A[4][2] = {}; f32x4 acc2A[3][4] = {}; f32x4 acc3A[2][2] = {};
    f32x4 acc1B[4][2] = {}; f32x4 acc2B[3][4] = {}; f32x4 acc3B[2][2] = {};

    #define BAR __syncthreads()
    ph_stage(Lm, lmA, poolA, dtab, true, bA, r0);                    BAR;  // 0
    ph_enc(XA, lmA, dtab, We, be);                                   BAR;  // 1
    ph_band1(XA, Y1hA, Y1lA, dtab);                                  BAR;  // 2
    ph_gemm1(Y1hA, Y1lA, wext, acc1A);                               BAR;  // 3
    ph_epi1(XA, acc1A, dtab, b1, 0);                                 BAR;  // 4
    ph_band2(XA, Y2hA, Y2lA, dtab, 0);
    ph_stage(Lm, lmB, poolB, dtab, false, bB, r0);                   BAR;  // 5
    ph_epi1(XA, acc1A, dtab, b1, 1);
    ph_enc(XB, lmB, dtab, We, be);                                   BAR;  // 6
    ph_band2(XA, Y2hA, Y2lA, dtab, 1);
    ph_band1(XB, Y1hB, Y1lB, dtab);                                  BAR;  // 7
    ph_gemm2(Y2hA, Y2lA, wext, acc2A);
    ph_gemm1(Y1hB, Y1lB, wext, acc1B);                               BAR;  // 8
    ph_epi2(XA, acc2A, dtab, b2, 0);
    ph_epi1(XB, acc1B, dtab, b1, 0);                                 BAR;  // 9
    ph_band3(XA, Y3hA, Y3lA, dtab);
    ph_band2(XB, Y2hB, Y2lB, dtab, 0);                               BAR;  // 10
    ph_gemm3(Y3hA, Y3lA, wext, acc3A, 0);
    ph_epi1(XB, acc1B, dtab, b1, 1);                                 BAR;  // 11
    ph_epi2(XA, acc2A, dtab, b2, 1);
    ph_band2(XB, Y2hB, Y2lB, dtab, 1);                               BAR;  // 12
    ph_band3(XA, Y3hA, Y3lA, dtab);
    ph_gemm2(Y2hB, Y2lB, wext, acc2B);                               BAR;  // 13
    ph_gemm3(Y3hA, Y3lA, wext, acc3A, 1);
    ph_epi2(XB, acc2B, dtab, b2, 0);                                 BAR;  // 14
    ph_pool(acc3A, poolA, b3, partial, bA, rt, r0);
    ph_band3(XB, Y3hB, Y3lB, dtab);                                  BAR;  // 15
    ph_gemm3(Y3hB, Y3lB, wext, acc3B, 0);                            BAR;  // 16
    ph_epi2(XB, acc2B, dtab, b2, 1);                                 BAR;  // 17
    ph_band3(XB, Y3hB, Y3lB, dtab);                                  BAR;  // 18
    ph_gemm3(Y3hB, Y3lB, wext, acc3B, 1);                            BAR;  // 19
    ph_pool(acc3B, poolB, b3, partial, bB, rt, r0);                        // 20
    #undef BAR
}

// ---------------------------------------------------------------------------
__global__ __launch_bounds__(256) void wconv(
    const float* __restrict__ W1, const float* __restrict__ W2,
    const float* __restrict__ W3, ushort_t* __restrict__ wext)
{
    int i = blockIdx.x * 256 + threadIdx.x;
    float w; int off_h, off_l, idx;
    if (i < 8192) {                       // W1: K=64,  N=128
        int k = i >> 7, n = i & 127;
        w = W1[i]; idx = frag_off(n, k, 1024);  off_h = W1H; off_l = W1L;
    } else if (i < 40960) {               // W2: K=128, N=256
        int j = i - 8192;
        int k = j >> 8, n = j & 255;
        w = W2[j]; idx = frag_off(n, k, 2048);  off_h = W2H; off_l = W2L;
    } else if (i < 73728) {               // W3: K=256, N=128
        int j = i - 40960;
        int k = j >> 7, n = j & 127;
        w = W3[j]; idx = frag_off(n, k, 4096);  off_h = W3H; off_l = W3L;
    } else return;
    __hip_bfloat16 hb = __float2bfloat16(w);
    float hf = __bfloat162float(hb);
    __hip_bfloat16 lb = __float2bfloat16(w - hf);
    wext[off_h + idx] = *(ushort_t*)&hb;
    wext[off_l + idx] = *(ushort_t*)&lb;
}

// ---------------------------------------------------------------------------
__global__ __launch_bounds__(512) void head_kernel(
    const float* __restrict__ partial, const float* __restrict__ Wf,
    const float* __restrict__ bf, const float* __restrict__ Wc,
    const float* __restrict__ bc, float* __restrict__ dout)
{
    __shared__ float gfs[128];
    __shared__ float feats[512];
    int b = blockIdx.x, t = threadIdx.x;
    if (t < 128) {
        const float* p = partial + (size_t)b * (8 * 128);
        float s = 0.f;
        #pragma unroll
        for (int tt = 0; tt < 8; ++tt) s += p[tt * 128 + t];
        s *= (1.0f / 468.0f);
        gfs[t] = s;
        dout[65792 + b * 128 + t] = s;       // graph_features
    }
    __syncthreads();
    float a = bf[t];
    for (int k = 0; k < 128; ++k) a += gfs[k] * Wf[k * 512 + t];
    a = fmaxf(a, 0.f);
    dout[256 + b * 512 + t] = a;             // features
    feats[t] = a;
    __syncthreads();
    if (t < 64) {
        float s0 = 0.f, s1 = 0.f;
        for (int c = t; c < 512; c += 64) {
            float f = feats[c];
            s0 += f * Wc[c * 2 + 0];
            s1 += f * Wc[c * 2 + 1];
        }
        #pragma unroll
        for (int off = 32; off; off >>= 1) {
            s0 += __shfl_down(s0, off);
            s1 += __shfl_down(s1, off);
        }
        if (t == 0) {
            dout[b * 2 + 0] = s0 + bc[0];
            dout[b * 2 + 1] = s1 + bc[1];
        }
    }
}

// ---------------------------------------------------------------------------
extern "C" void kernel_launch(void* const* d_in, const int* in_sizes, int n_in,
                              void* d_out, int out_size, void* d_ws, size_t ws_size,
                              hipStream_t stream)
{
    const float* landmarks = (const float*)d_in[0];
    const float* W_enc     = (const float*)d_in[1];
    const float* b_enc     = (const float*)d_in[2];
    const float* W1        = (const float*)d_in[3];
    const float* b1        = (const float*)d_in[4];
    const float* W2        = (const float*)d_in[5];
    const float* b2        = (const float*)d_in[6];
    const float* W3        = (const float*)d_in[7];
    const float* b3        = (const float*)d_in[8];
    const float* W_fus     = (const float*)d_in[9];
    const float* b_fus     = (const float*)d_in[10];
    const float* W_cls     = (const float*)d_in[11];
    const float* b_cls     = (const float*)d_in[12];
    float* out = (float*)d_out;

    char* ws = (char*)d_ws;
    ushort_t* wext = (ushort_t*)(ws + 0);        // 294,912 B
    float* partial = (float*)(ws + 294912);      // 524,288 B

    wconv<<<288, 256, 0, stream>>>(W1, W2, W3, wext);
    fused2<<<dim3(8, 64), 512, 0, stream>>>(
        landmarks, wext, W_enc, b_enc, b1, b2, b3, partial);
    head_kernel<<<128, 512, 0, stream>>>(partial, W_fus, b_fus, W_cls, b_cls, out);
}

// Round 19
// 83.733 us; speedup vs baseline: 1.7688x; 1.7688x over previous
//
#include <hip/hip_runtime.h>
#include <hip/hip_bf16.h>

typedef __bf16 bf16x8 __attribute__((ext_vector_type(8)));
typedef float  f32x4  __attribute__((ext_vector_type(4)));
typedef unsigned short ushort_t;

#define NN 468

// wext element offsets (ushort), fragment-major planes (NOT swizzled)
#define W1H 0
#define W1L 8192
#define W2H 16384
#define W2L 49152
#define W3H 81920
#define W3L 114688

// ---- LDS layout (64-row tile, hand-overlaid; total 78,752 B) --------------
// X0 [118][68]f32=32096 @0 | X1 [100][68]f32=27200 @0 | X2 [82][132]f32=43296 @0
// Y1 @32096 (2x14336) | Y2 @27200 (2x24576 full-K) | Y3 @43296 (2x16384)
// lmst @76352 | dtab @77768 | pool @78240
// Pairwise-live: {X0,Y1} {X1,Y2} {X2,Y3} disjoint; Y lifetimes barrier-split.
#define L_Y1   32096
#define L_Y2   27200
#define L_Y3   43296
#define L_LM   76352
#define L_DTAB 77768
#define L_POOL 78240

#define MFMA3(d, ah, al, wh, wl)                                        \
    d = __builtin_amdgcn_mfma_f32_16x16x32_bf16(ah, wh, d, 0, 0, 0);    \
    d = __builtin_amdgcn_mfma_f32_16x16x32_bf16(ah, wl, d, 0, 0, 0);    \
    d = __builtin_amdgcn_mfma_f32_16x16x32_bf16(al, wh, d, 0, 0, 0);

// ---------------------------------------------------------------------------
__device__ __forceinline__ void pack_split4(const float* y,
                                            ushort_t* hdst, ushort_t* ldst) {
    ushort_t h[4], l[4];
    #pragma unroll
    for (int j = 0; j < 4; ++j) {
        __hip_bfloat16 hb = __float2bfloat16(y[j]);
        float hf = __bfloat162float(hb);
        __hip_bfloat16 lb = __float2bfloat16(y[j] - hf);
        h[j] = *(ushort_t*)&hb; l[j] = *(ushort_t*)&lb;
    }
    uint2 hv = make_uint2((unsigned)h[0] | ((unsigned)h[1] << 16),
                          (unsigned)h[2] | ((unsigned)h[3] << 16));
    uint2 lv = make_uint2((unsigned)l[0] | ((unsigned)l[1] << 16),
                          (unsigned)l[2] | ((unsigned)l[3] << 16));
    *(uint2*)hdst = hv;
    *(uint2*)ldst = lv;
}

__device__ __forceinline__ int frag_off(int r, int k, int K16) {
    return (r >> 4) * K16 + (k >> 5) * 512 + ((k >> 3) & 3) * 128
         + (r & 15) * 8 + (k & 7);
}

// swizzled Y-plane offset (LDS): unit' = q*16 + ((r ^ 2q) & 15)
__device__ __forceinline__ int ywoff(int r, int k4, int K16) {
    int q = (k4 >> 3) & 3;
    int u = q * 16 + (((r & 15) ^ (q << 1)) & 15);
    return (r >> 4) * K16 + (k4 >> 5) * 512 + u * 8 + (k4 & 7);
}

// ---------------------------------------------------------------------------
// fused: full 3-layer GCN chain for one (64-row tile, batch) in LDS.
// 1024 threads = 16 waves (wm = w&1 over m, wn = w>>1 in 0..7 over n).
// Frames (dtab[t] = dinv(r0-27+t), t<118):
//   X0 l0 : gr=r0-27+l0 (0..117) | Y1/X1 lr1: gr=r0-18+lr1 (0..99, pad 112)
//   Y2/X2 lr2: gr=r0-9+lr2 (0..81, pad 96) | Y3 lr3: gr=r0+lr3 (0..63)
// Per-wave acc: acc1[4]=16, acc2[3][2]=24, acc3[2]=8 regs (half of R16).
// launch_bounds(1024,4): 128-reg cap — NEVER raise min-waves (R10/R13 spill).
// ---------------------------------------------------------------------------
__global__ __launch_bounds__(1024, 4) void fused(
    const float* __restrict__ Lm, const ushort_t* __restrict__ wext,
    const float* __restrict__ We, const float* __restrict__ be,
    const float* __restrict__ b1, const float* __restrict__ b2,
    const float* __restrict__ b3, float* __restrict__ partial)
{
    __shared__ __align__(16) char lds[78752];
    float*    X    = (float*)(lds);            // X0 / X1 / X2 overlaid
    ushort_t* Y1h  = (ushort_t*)(lds + L_Y1);  ushort_t* Y1l = Y1h + 7168;
    ushort_t* Y2h  = (ushort_t*)(lds + L_Y2);  ushort_t* Y2l = Y2h + 12288;
    ushort_t* Y3h  = (ushort_t*)(lds + L_Y3);  ushort_t* Y3l = Y3h + 8192;
    float*    lmst = (float*)(lds + L_LM);
    float*    dtab = (float*)(lds + L_DTAB);
    float*    pool = (float*)(lds + L_POOL);

    const int tid  = threadIdx.x;
    const int lane = tid & 63;
    const int wave = tid >> 6;                 // 0..15
    const int wm = wave & 1, wn = wave >> 1;   // wn in 0..7
    const int l15 = lane & 15, lg = lane >> 4;
    const int lswz = (lane & 48) + (((lane & 15) ^ ((lane >> 4) << 1)) & 15);
    const int rt = blockIdx.x, b = blockIdx.y;
    const int r0 = rt * 64;

    // ---------------- stage: dinv table, landmarks, pool init -------------
    if (tid < 118) {
        int ri = r0 - 27 + tid;
        float dv = 0.f;
        if (ri >= 0 && ri < NN) {
            int lo = ri - 9; if (lo < 0) lo = 0;
            int hi = ri + 9; if (hi > NN - 1) hi = NN - 1;
            dv = 1.0f / sqrtf((float)(hi - lo + 1));
        }
        dtab[tid] = dv;
    }
    if (tid < 354) {
        int g = (r0 - 27) * 3 + tid;
        lmst[tid] = (g >= 0 && g < NN * 3) ? Lm[(size_t)b * (NN * 3) + g] : 0.f;
    }
    if (tid < 128) pool[tid] = 0.f;
    __syncthreads();

    // ---------------- enc: X0[118][68] = enc(row) * dinv -------------------
    {
        const int c = tid & 63;
        const float w0 = We[c], w1 = We[64 + c], w2 = We[128 + c], bk = be[c];
        for (int l0 = tid >> 6; l0 < 118; l0 += 16) {
            float x = bk + lmst[l0*3]*w0 + lmst[l0*3+1]*w1 + lmst[l0*3+2]*w2;
            X[l0 * 68 + c] = x * dtab[l0];
        }
    }
    __syncthreads();    // X0 ready; lmst dead

    // ---------------- band1: X0 -> Y1 [100 rows][64], pad to 112 -----------
    {
        const int c4 = (tid & 15) << 2;
        const int base = (tid >> 4) * 2;       // 64 groups x 2 rows = 128>=112
        if (base < 100) {
            f32x4 ws = {};
            #pragma unroll
            for (int d = 0; d < 19; ++d)
                ws += *(const f32x4*)(X + (base + d) * 68 + c4);
            #pragma unroll
            for (int rr = 0; rr < 2; ++rr) {
                int row = base + rr;
                if (rr) ws += *(const f32x4*)(X + (row + 18) * 68 + c4)
                            - *(const f32x4*)(X + (row - 1)  * 68 + c4);
                float dv = dtab[row + 9];
                float y4[4] = {ws[0]*dv, ws[1]*dv, ws[2]*dv, ws[3]*dv};
                int off = ywoff(row, c4, 1024);
                pack_split4(y4, Y1h + off, Y1l + off);
            }
        } else if (base < 112) {               // zero pad rows 100..111
            float z4[4] = {0.f, 0.f, 0.f, 0.f};
            #pragma unroll
            for (int rr = 0; rr < 2; ++rr) {
                int row = base + rr;
                if (row < 112) {
                    int off = ywoff(row, c4, 1024);
                    pack_split4(z4, Y1h + off, Y1l + off);
                }
            }
        }
    }
    __syncthreads();

    // ---------------- GEMM1: Y1(7 tiles) @ W1 ------------------------------
    // m: t = wm*4+mt clamp 6 (dup benign); n: ntile = wn (one per wave)
    f32x4 acc1[4] = {};
    __builtin_amdgcn_s_setprio(1);
    #pragma unroll
    for (int kt = 0; kt < 2; ++kt) {
        bf16x8 a[4][2];
        #pragma unroll
        for (int mt = 0; mt < 4; ++mt) {
            int t = wm*4 + mt; if (t > 6) t = 6;
            int off = t * 1024 + kt * 512 + lswz * 8;
            a[mt][0] = *(const bf16x8*)(Y1h + off);
            a[mt][1] = *(const bf16x8*)(Y1l + off);
        }
        int woff = wn * 1024 + kt * 512 + lane * 8;
        bf16x8 wh = *(const bf16x8*)(wext + W1H + woff);
        bf16x8 wl = *(const bf16x8*)(wext + W1L + woff);
        #pragma unroll
        for (int mt = 0; mt < 4; ++mt) {
            MFMA3(acc1[mt], a[mt][0], a[mt][1], wh, wl);
        }
    }
    __builtin_amdgcn_s_setprio(0);
    // no barrier: epi1 writes X1 [0,27200) — disjoint from Y1 @32096

    // ------- kc loop: epi1(kc) -> X1 -> band2(kc) -> Y2 cols kc*64.. -------
    #pragma unroll
    for (int kc = 0; kc < 2; ++kc) {
        // epi1(kc): waves with wn in [kc*4, kc*4+4) write their n-tile
        if ((wn >> 2) == kc) {
            int gcol = wn*16 + l15;            // global col = ntile wn
            int cl   = (wn & 3)*16 + l15;      // col within 64-chunk
            float bv = b1[gcol];
            #pragma unroll
            for (int mt = 0; mt < 4; ++mt) {
                int t = wm*4 + mt; if (t > 6) t = 6;
                #pragma unroll
                for (int r = 0; r < 4; ++r) {
                    int lr1 = t*16 + lg*4 + r;
                    if (lr1 < 100)
                        X[lr1*68 + cl] =
                            dtab[lr1 + 9] * fmaxf(acc1[mt][r] + bv, 0.f);
                }
            }
        }
        __syncthreads();   // X1 chunk ready; (kc=0) fences Y1 reads vs Y2 writes

        // band2(kc): X1 -> Y2 [82 rows][kc*64..+64), pad rows to 96
        {
            const int c4   = (tid & 15) << 2;
            const int base = (tid >> 4) * 2;   // active for base < 96
            if (base < 96) {
                f32x4 ws = {};
                if (base < 82) {
                    #pragma unroll
                    for (int d = 0; d < 19; ++d)
                        ws += *(const f32x4*)(X + (base + d) * 68 + c4);
                }
                #pragma unroll
                for (int rr = 0; rr < 2; ++rr) {
                    int row = base + rr;
                    if (row < 96) {
                        float y4[4] = {0.f, 0.f, 0.f, 0.f};
                        if (row < 82) {
                            if (rr) ws += *(const f32x4*)(X + (row + 18) * 68 + c4)
                                        - *(const f32x4*)(X + (row - 1)  * 68 + c4);
                            float dv = dtab[row + 18];
                            y4[0] = ws[0]*dv; y4[1] = ws[1]*dv;
                            y4[2] = ws[2]*dv; y4[3] = ws[3]*dv;
                        }
                        int off = ywoff(row, kc*64 + c4, 2048);
                        pack_split4(y4, Y2h + off, Y2l + off);
                    }
                }
            }
        }
        __syncthreads();   // Y2 chunk ready; X1 reads done
    }

    // ---------------- GEMM2: Y2(6 tiles, K=128) @ W2 — one fat phase -------
    f32x4 acc2[3][2] = {};
    __builtin_amdgcn_s_setprio(1);
    #pragma unroll
    for (int kt = 0; kt < 4; ++kt) {
        bf16x8 a[3][2];
        #pragma unroll
        for (int mt = 0; mt < 3; ++mt) {
            int off = (wm*3 + mt) * 2048 + kt * 512 + lswz * 8;
            a[mt][0] = *(const bf16x8*)(Y2h + off);
            a[mt][1] = *(const bf16x8*)(Y2l + off);
        }
        #pragma unroll
        for (int nt = 0; nt < 2; ++nt) {
            int woff = (nt*8 + wn) * 2048 + kt * 512 + lane * 8;
            bf16x8 wh = *(const bf16x8*)(wext + W2H + woff);
            bf16x8 wl = *(const bf16x8*)(wext + W2L + woff);
            #pragma unroll
            for (int mt = 0; mt < 3; ++mt) {
                MFMA3(acc2[mt][nt], a[mt][0], a[mt][1], wh, wl);
            }
        }
    }
    __builtin_amdgcn_s_setprio(0);
    __syncthreads();   // all Y2 reads done before epi2(0) writes X2 (overlap)

    // ------- nc loop: [GEMM3(nc-1) ∥] epi2 -> X2 -> band3 -> Y3 -> GEMM3 ---
    f32x4 acc3[2] = {};
    #pragma unroll
    for (int nc = 0; nc < 2; ++nc) {
        if (nc == 1) {
            __builtin_amdgcn_s_setprio(1);
            #pragma unroll
            for (int kt = 0; kt < 4; ++kt) {
                bf16x8 a0[2], a1[2];
                #pragma unroll
                for (int mt = 0; mt < 2; ++mt) {
                    int aoff = (wm*2 + mt) * 2048 + kt * 512 + lswz * 8;
                    a0[mt] = *(const bf16x8*)(Y3h + aoff);
                    a1[mt] = *(const bf16x8*)(Y3l + aoff);
                }
                int woff = wn * 4096 + (0*4 + kt) * 512 + lane * 8;
                bf16x8 wh = *(const bf16x8*)(wext + W3H + woff);
                bf16x8 wl = *(const bf16x8*)(wext + W3L + woff);
                #pragma unroll
                for (int mt = 0; mt < 2; ++mt) {
                    MFMA3(acc3[mt], a0[mt], a1[mt], wh, wl);
                }
            }
            __builtin_amdgcn_s_setprio(0);
        }
        // epi2(nc): acc2[:,nc] -> X2[82][132] premult (all waves)
        {
            int gcol = (nc*8 + wn)*16 + l15;
            int cl   = wn*16 + l15;
            float bv = b2[gcol];
            #pragma unroll
            for (int mt = 0; mt < 3; ++mt)
            #pragma unroll
            for (int r = 0; r < 4; ++r) {
                int lr2 = (wm*3 + mt)*16 + lg*4 + r;
                if (lr2 < 82)
                    X[lr2*132 + cl] =
                        dtab[lr2 + 18] * fmaxf(acc2[mt][nc][r] + bv, 0.f);
            }
        }
        __syncthreads();

        // band3(nc): X2 -> Y3 [64 rows][128]
        {
            const int c4   = (tid & 31) << 2;  // 128 cols
            const int base = (tid >> 5) * 2;   // 32 groups x 2 rows
            f32x4 ws = {};
            #pragma unroll
            for (int d = 0; d < 19; ++d)
                ws += *(const f32x4*)(X + (base + d) * 132 + c4);
            #pragma unroll
            for (int rr = 0; rr < 2; ++rr) {
                int row = base + rr;
                if (rr) ws += *(const f32x4*)(X + (row + 18) * 132 + c4)
                            - *(const f32x4*)(X + (row - 1)  * 132 + c4);
                float dv = dtab[row + 27];
                float y4[4] = {ws[0]*dv, ws[1]*dv, ws[2]*dv, ws[3]*dv};
                int off = ywoff(row, c4, 2048);
                pack_split4(y4, Y3h + off, Y3l + off);
            }
        }
        __syncthreads();
    }

    // ---- trailing GEMM3(nc=1) ----
    __builtin_amdgcn_s_setprio(1);
    #pragma unroll
    for (int kt = 0; kt < 4; ++kt) {
        bf16x8 a0[2], a1[2];
        #pragma unroll
        for (int mt = 0; mt < 2; ++mt) {
            int aoff = (wm*2 + mt) * 2048 + kt * 512 + lswz * 8;
            a0[mt] = *(const bf16x8*)(Y3h + aoff);
            a1[mt] = *(const bf16x8*)(Y3l + aoff);
        }
        int woff = wn * 4096 + (1*4 + kt) * 512 + lane * 8;
        bf16x8 wh = *(const bf16x8*)(wext + W3H + woff);
        bf16x8 wl = *(const bf16x8*)(wext + W3L + woff);
        #pragma unroll
        for (int mt = 0; mt < 2; ++mt) {
            MFMA3(acc3[mt], a0[mt], a1[mt], wh, wl);
        }
    }
    __builtin_amdgcn_s_setprio(0);

    // ---------------- pool: column sums of relu(acc3 + b3) -----------------
    {
        float bv = b3[wn*16 + l15];
        float cs = 0.f;
        #pragma unroll
        for (int mt = 0; mt < 2; ++mt)
        #pragma unroll
        for (int r = 0; r < 4; ++r) {
            int gr = r0 + (wm*2 + mt)*16 + lg*4 + r;
            if (gr < NN) cs += fmaxf(acc3[mt][r] + bv, 0.f);
        }
        cs += __shfl_xor(cs, 16);
        cs += __shfl_xor(cs, 32);
        if (lane < 16) atomicAdd(&pool[wn*16 + lane], cs);
    }
    __syncthreads();
    if (tid < 128) partial[((size_t)b * 8 + rt) * 128 + tid] = pool[tid];
}

// ---------------------------------------------------------------------------
// wconv: W fp32 [K][N] -> bf16 hi/lo planes, fragment layout (unswizzled)
// ---------------------------------------------------------------------------
__global__ __launch_bounds__(256) void wconv(
    const float* __restrict__ W1, const float* __restrict__ W2,
    const float* __restrict__ W3, ushort_t* __restrict__ wext)
{
    int i = blockIdx.x * 256 + threadIdx.x;
    float w; int off_h, off_l, idx;
    if (i < 8192) {                       // W1: K=64,  N=128
        int k = i >> 7, n = i & 127;
        w = W1[i]; idx = frag_off(n, k, 1024);  off_h = W1H; off_l = W1L;
    } else if (i < 40960) {               // W2: K=128, N=256
        int j = i - 8192;
        int k = j >> 8, n = j & 255;
        w = W2[j]; idx = frag_off(n, k, 2048);  off_h = W2H; off_l = W2L;
    } else if (i < 73728) {               // W3: K=256, N=128
        int j = i - 40960;
        int k = j >> 7, n = j & 127;
        w = W3[j]; idx = frag_off(n, k, 4096);  off_h = W3H; off_l = W3L;
    } else return;
    __hip_bfloat16 hb = __float2bfloat16(w);
    float hf = __bfloat162float(hb);
    __hip_bfloat16 lb = __float2bfloat16(w - hf);
    wext[off_h + idx] = *(ushort_t*)&hb;
    wext[off_l + idx] = *(ushort_t*)&lb;
}

// ---------------------------------------------------------------------------
// head: gf = mean-pool reduce; features = relu(gf@Wf+bf); out = feats@Wc+bc
// ---------------------------------------------------------------------------
__global__ __launch_bounds__(512) void head_kernel(
    const float* __restrict__ partial, const float* __restrict__ Wf,
    const float* __restrict__ bf, const float* __restrict__ Wc,
    const float* __restrict__ bc, float* __restrict__ dout)
{
    __shared__ float gfs[128];
    __shared__ float feats[512];
    int b = blockIdx.x, t = threadIdx.x;
    if (t < 128) {
        const float* p = partial + (size_t)b * (8 * 128);
        float s = 0.f;
        #pragma unroll
        for (int tt = 0; tt < 8; ++tt) s += p[tt * 128 + t];
        s *= (1.0f / 468.0f);
        gfs[t] = s;
        dout[65792 + b * 128 + t] = s;       // graph_features
    }
    __syncthreads();
    float a = bf[t];
    for (int k = 0; k < 128; ++k) a += gfs[k] * Wf[k * 512 + t];
    a = fmaxf(a, 0.f);
    dout[256 + b * 512 + t] = a;             // features
    feats[t] = a;
    __syncthreads();
    if (t < 64) {
        float s0 = 0.f, s1 = 0.f;
        for (int c = t; c < 512; c += 64) {
            float f = feats[c];
            s0 += f * Wc[c * 2 + 0];
            s1 += f * Wc[c * 2 + 1];
        }
        #pragma unroll
        for (int off = 32; off; off >>= 1) {
            s0 += __shfl_down(s0, off);
            s1 += __shfl_down(s1, off);
        }
        if (t == 0) {
            dout[b * 2 + 0] = s0 + bc[0];
            dout[b * 2 + 1] = s1 + bc[1];
        }
    }
}

// ---------------------------------------------------------------------------
extern "C" void kernel_launch(void* const* d_in, const int* in_sizes, int n_in,
                              void* d_out, int out_size, void* d_ws, size_t ws_size,
                              hipStream_t stream)
{
    const float* landmarks = (const float*)d_in[0];
    const float* W_enc     = (const float*)d_in[1];
    const float* b_enc     = (const float*)d_in[2];
    const float* W1        = (const float*)d_in[3];
    const float* b1        = (const float*)d_in[4];
    const float* W2        = (const float*)d_in[5];
    const float* b2        = (const float*)d_in[6];
    const float* W3        = (const float*)d_in[7];
    const float* b3        = (const float*)d_in[8];
    const float* W_fus     = (const float*)d_in[9];
    const float* b_fus     = (const float*)d_in[10];
    const float* W_cls     = (const float*)d_in[11];
    const float* b_cls     = (const float*)d_in[12];
    float* out = (float*)d_out;

    char* ws = (char*)d_ws;
    ushort_t* wext = (ushort_t*)(ws + 0);        // 294,912 B
    float* partial = (float*)(ws + 294912);      // 524,288 B

    wconv<<<288, 256, 0, stream>>>(W1, W2, W3, wext);
    fused<<<dim3(8, 128), 1024, 0, stream>>>(
        landmarks, wext, W_enc, b_enc, b1, b2, b3, partial);
    head_kernel<<<128, 512, 0, stream>>>(partial, W_fus, b_fus, W_cls, b_cls, out);
}